// Round 5
// baseline (152130.017 us; speedup 1.0000x reference)
//
#include <hip/hip_runtime.h>
#include <hip/hip_bf16.h>

// ============================================================================
// Seq2seq: bi-GRU encoder (T=8192, H=I=1024) + attention decoder (L=64).
// DTYPE-AGNOSTIC: a detect kernel classifies d_in storage (fp32 vs bf16) from
// x's bit patterns; all d_in/d_out-touching kernels are templated on MODE and
// launched twice (mismatched instantiation early-exits on the ws flag).
//  - gi = x@Wih.T batched into one GEMM (8192x1024 @ 1024x6144), bf16 scratch.
//  - attention softmax shift-invariance => attn/context constant across all
//    64 decoder steps; computed once.
//  - recurrence: persistent kernel + hierarchical grid barrier, plain launch
//    (proven to complete in round 4; cooperative launch never executed).
// Workspace ~160 MiB (proven in-bounds).
// ============================================================================
static constexpr size_t GI_ELEMS   = (size_t)8192 * 6144;       // bf16 elems
static constexpr size_t OFF_ENC2   = GI_ELEMS / 2;              // float idx
static constexpr size_t OFF_HF     = OFF_ENC2 + 16777216;
static constexpr size_t OFF_HB     = OFF_HF + 2048;
static constexpr size_t OFF_SCORES = OFF_HB + 2048;
static constexpr size_t OFF_CTX    = OFF_SCORES + 8192;
static constexpr size_t OFF_GICTX  = OFF_CTX + 2048;
static constexpr size_t OFF_DH     = OFF_GICTX + 4096;
static constexpr size_t OFF_DECIN  = OFF_DH + 2048;
static constexpr size_t OFF_LOGITS = OFF_DECIN + 2048;
static constexpr size_t OFF_BAR    = OFF_LOGITS + 2048;         // 2048 u32
static constexpr size_t OFF_FLAG   = OFF_BAR + 2048;            // 16 u32

typedef __hip_bfloat16 bf16_t;
struct alignas(8) bh4 { bf16_t v[4]; };
__device__ __forceinline__ float bf2f(bf16_t v) { return __bfloat162float(v); }

// MODE 0: buffers are fp32.  MODE 1: buffers are bf16.
template <int MODE>
__device__ __forceinline__ float ld1(const void* p, size_t i) {
  if (MODE) return bf2f(((const bf16_t*)p)[i]);
  return ((const float*)p)[i];
}
template <int MODE>
__device__ __forceinline__ float4 ld4(const void* p, size_t i) {  // i % 4 == 0
  if (MODE) {
    bh4 q = *(const bh4*)((const bf16_t*)p + i);
    return make_float4(bf2f(q.v[0]), bf2f(q.v[1]), bf2f(q.v[2]), bf2f(q.v[3]));
  }
  return *(const float4*)((const float*)p + i);
}
template <int MODE>
__device__ __forceinline__ void st1(void* p, size_t i, float v) {
  if (MODE) ((bf16_t*)p)[i] = __float2bfloat16(v);
  else ((float*)p)[i] = v;
}

// ----------------------------------------------------------------------------
// Classify storage: fp32 words of N(0,1) data have exponent field in [90,150]
// (values 1e-11..8e6) essentially always; bf16-pair words land at ~220..255.
// ----------------------------------------------------------------------------
__global__ void k_detect(const unsigned* __restrict__ xbits, unsigned* flag) {
  __shared__ int cnt;
  if (threadIdx.x == 0) cnt = 0;
  __syncthreads();
  unsigned u = xbits[threadIdx.x];  // 256 words = first 1 KB of x
  unsigned e = (u >> 23) & 0xFFu;
  if (e >= 90u && e <= 150u) atomicAdd(&cnt, 1);
  __syncthreads();
  if (threadIdx.x == 0) flag[0] = (cnt >= 192) ? 0u : 1u;
}

// ----------------------------------------------------------------------------
// Hierarchical grid barrier over a 512-u32 region (group ctrs / root / sense).
// ----------------------------------------------------------------------------
__device__ __forceinline__ void grid_barrier(unsigned* region, int grp,
                                             unsigned gs, unsigned ng,
                                             unsigned* phase, unsigned sense_base) {
  __syncthreads();
  if (threadIdx.x == 0) {
    unsigned p = (*phase)++;
    unsigned t = __hip_atomic_fetch_add(&region[grp * 16], 1u, __ATOMIC_ACQ_REL,
                                        __HIP_MEMORY_SCOPE_AGENT);
    if ((t % gs) == gs - 1u) {
      unsigned r = __hip_atomic_fetch_add(&region[256], 1u, __ATOMIC_ACQ_REL,
                                          __HIP_MEMORY_SCOPE_AGENT);
      if ((r % ng) == ng - 1u) {
        for (unsigned i = 0; i < ng; ++i)
          __hip_atomic_store(&region[320 + i * 16], sense_base + p + 1u,
                             __ATOMIC_RELEASE, __HIP_MEMORY_SCOPE_AGENT);
      }
    }
    while ((int)(__hip_atomic_load(&region[320 + grp * 16], __ATOMIC_RELAXED,
                                   __HIP_MEMORY_SCOPE_AGENT) -
                 (sense_base + p + 1u)) < 0) {
      __builtin_amdgcn_s_sleep(1);
    }
    __builtin_amdgcn_fence(__ATOMIC_ACQUIRE, "agent");
  }
  __syncthreads();
}

// ----------------------------------------------------------------------------
template <int MODE>
__global__ __launch_bounds__(256) void k_init(const unsigned* __restrict__ md,
                                              float* hf, float* hb,
                                              const void* __restrict__ h0,
                                              float* decin, unsigned* bars) {
  if (md[0] != (unsigned)MODE) return;
  int i = blockIdx.x * 256 + threadIdx.x;  // grid 16*256
  if (i < 1024) { hf[i] = ld1<MODE>(h0, i); hb[i] = ld1<MODE>(h0, 1024 + i); }
  if (i < 2048) decin[i] = 0.f;
  if (i < 2048) bars[i] = 0u;
}

// ----------------------------------------------------------------------------
// GI = X @ [Wih_f; Wih_b]^T + bias.  64x64 tile, 4x4 microtile, fp32 math.
// ----------------------------------------------------------------------------
template <int MODE>
__global__ __launch_bounds__(256) void k_gemm_gi(
    const unsigned* __restrict__ md, const void* __restrict__ X,
    const void* __restrict__ Wf, const void* __restrict__ Wb,
    const void* __restrict__ bf, const void* __restrict__ bb,
    bf16_t* __restrict__ GI) {
  if (md[0] != (unsigned)MODE) return;
  __shared__ __align__(16) float As[16][68];
  __shared__ __align__(16) float Bs[16][68];
  const int m0 = blockIdx.x * 64;
  const int n0 = blockIdx.y * 64;
  const int tid = threadIdx.x;
  const int tx = tid & 15, ty = tid >> 4;
  const int lm = tid >> 2, lk = (tid & 3) * 4;
  const void* Wsel = (n0 < 3072) ? Wf : Wb;
  const void* bsel = (n0 < 3072) ? bf : bb;
  const int nadj = (n0 < 3072) ? n0 : (n0 - 3072);
  float acc[4][4];
#pragma unroll
  for (int i = 0; i < 4; ++i)
#pragma unroll
    for (int j = 0; j < 4; ++j) acc[i][j] = 0.f;
  for (int k0 = 0; k0 < 1024; k0 += 16) {
    float4 av = ld4<MODE>(X, (size_t)(m0 + lm) * 1024 + k0 + lk);
    float4 bv = ld4<MODE>(Wsel, (size_t)(nadj + lm) * 1024 + k0 + lk);
    __syncthreads();
    As[lk + 0][lm] = av.x; As[lk + 1][lm] = av.y; As[lk + 2][lm] = av.z; As[lk + 3][lm] = av.w;
    Bs[lk + 0][lm] = bv.x; Bs[lk + 1][lm] = bv.y; Bs[lk + 2][lm] = bv.z; Bs[lk + 3][lm] = bv.w;
    __syncthreads();
#pragma unroll
    for (int kk = 0; kk < 16; ++kk) {
      float4 a = *(const float4*)&As[kk][ty * 4];
      float4 b = *(const float4*)&Bs[kk][tx * 4];
      acc[0][0] += a.x * b.x; acc[0][1] += a.x * b.y; acc[0][2] += a.x * b.z; acc[0][3] += a.x * b.w;
      acc[1][0] += a.y * b.x; acc[1][1] += a.y * b.y; acc[1][2] += a.y * b.z; acc[1][3] += a.y * b.w;
      acc[2][0] += a.z * b.x; acc[2][1] += a.z * b.y; acc[2][2] += a.z * b.z; acc[2][3] += a.z * b.w;
      acc[3][0] += a.w * b.x; acc[3][1] += a.w * b.y; acc[3][2] += a.w * b.z; acc[3][3] += a.w * b.w;
    }
  }
  float b0 = ld1<MODE>(bsel, nadj + tx * 4 + 0), b1 = ld1<MODE>(bsel, nadj + tx * 4 + 1);
  float b2 = ld1<MODE>(bsel, nadj + tx * 4 + 2), b3 = ld1<MODE>(bsel, nadj + tx * 4 + 3);
#pragma unroll
  for (int i = 0; i < 4; ++i) {
    bh4 o;
    o.v[0] = __float2bfloat16(acc[i][0] + b0);
    o.v[1] = __float2bfloat16(acc[i][1] + b1);
    o.v[2] = __float2bfloat16(acc[i][2] + b2);
    o.v[3] = __float2bfloat16(acc[i][3] + b3);
    *(bh4*)(GI + (size_t)(m0 + ty * 4 + i) * 6144 + n0 + tx * 4) = o;
  }
}

// ----------------------------------------------------------------------------
// Both GRU recurrences, lockstepped per direction (separate barrier regions).
// 512 blocks x 256 thr (2 blocks/CU). Block owns 4 hidden idx = 12 Whh rows
// in LDS (fp32). Wave w: 3 gate-row dots, butterfly-reduce, lane 0 gates.
// ----------------------------------------------------------------------------
template <int MODE>
__global__ __launch_bounds__(256, 2) void k_recurrence(
    const unsigned* __restrict__ md, const bf16_t* __restrict__ GI,
    const void* __restrict__ Whh_f, const void* __restrict__ Whh_b,
    const void* __restrict__ bhh_f, const void* __restrict__ bhh_b,
    float* __restrict__ enc2, float* hf, float* hb, unsigned* bars) {
  if (md[0] != (unsigned)MODE) return;
  __shared__ __align__(16) float w[12][1024];
  __shared__ __align__(16) float hsh[1024];
  __shared__ float gish[12];
  __shared__ float bsh[12];
  const int b = blockIdx.x;
  const int dir = b >> 8;
  const int bb = b & 255;
  const int j0 = bb * 4;
  const int tid = threadIdx.x;
  const int wv = tid >> 6, lane = tid & 63;
  const int grp = bb >> 5;      // 8 groups of 32 per direction
  unsigned* region = bars + dir * 512;
  const void* Whh = dir ? Whh_b : Whh_f;
  const void* bhh = dir ? bhh_b : bhh_f;
  float* hbuf = dir ? hb : hf;

#pragma unroll
  for (int r = 0; r < 12; ++r) {
    int g = r >> 2, jj = r & 3;
    float4 q = ld4<MODE>(Whh, (size_t)(g * 1024 + j0 + jj) * 1024 + tid * 4);
    w[r][tid * 4 + 0] = q.x; w[r][tid * 4 + 1] = q.y;
    w[r][tid * 4 + 2] = q.z; w[r][tid * 4 + 3] = q.w;
  }
  if (tid < 12) {
    int g = tid >> 2, jj = tid & 3;
    bsh[tid] = ld1<MODE>(bhh, g * 1024 + j0 + jj);
  }
  float gpre = 0.f;
  size_t gcol = 0;
  if (tid < 12) {
    int g = tid >> 2, jj = tid & 3;
    gcol = (size_t)(dir ? 3072 : 0) + g * 1024 + j0 + jj;
    gpre = bf2f(GI[(size_t)(dir ? 8191 : 0) * 6144 + gcol]);
  }
  unsigned sense_base = __hip_atomic_load(&region[320 + grp * 16], __ATOMIC_RELAXED,
                                          __HIP_MEMORY_SCOPE_AGENT);
  unsigned phase = 0;

  for (int t = 0; t < 8192; ++t) {
    const float* hrd = hbuf + (t & 1) * 1024;
    float* hwr = hbuf + ((t + 1) & 1) * 1024;
    ((float4*)hsh)[tid] = ((const float4*)hrd)[tid];
    if (tid < 12) gish[tid] = gpre;
    __syncthreads();
    if (tid < 12 && t < 8191) {
      size_t row = dir ? (size_t)(8190 - t) : (size_t)(t + 1);
      gpre = bf2f(GI[row * 6144 + gcol]);
    }
    float a0 = 0.f, a1 = 0.f, a2 = 0.f;
    const float4* h4 = (const float4*)hsh;
    const float4* w0 = (const float4*)&w[0 + wv][0];
    const float4* w1 = (const float4*)&w[4 + wv][0];
    const float4* w2 = (const float4*)&w[8 + wv][0];
#pragma unroll
    for (int k = 0; k < 4; ++k) {
      int idx = lane + 64 * k;
      float4 hv = h4[idx];
      float4 x0 = w0[idx], x1 = w1[idx], x2 = w2[idx];
      a0 += hv.x * x0.x + hv.y * x0.y + hv.z * x0.z + hv.w * x0.w;
      a1 += hv.x * x1.x + hv.y * x1.y + hv.z * x1.z + hv.w * x1.w;
      a2 += hv.x * x2.x + hv.y * x2.y + hv.z * x2.z + hv.w * x2.w;
    }
#pragma unroll
    for (int off = 32; off; off >>= 1) {
      a0 += __shfl_xor(a0, off);
      a1 += __shfl_xor(a1, off);
      a2 += __shfl_xor(a2, off);
    }
    if (lane == 0) {
      int jj = wv, j = j0 + jj;
      float hr = a0 + bsh[jj];
      float hz = a1 + bsh[4 + jj];
      float hn = a2 + bsh[8 + jj];
      float ir = gish[jj], iz = gish[4 + jj], inn = gish[8 + jj];
      float rr = 1.f / (1.f + expf(-(ir + hr)));
      float zz = 1.f / (1.f + expf(-(iz + hz)));
      float nn = tanhf(inn + rr * hn);
      float hnew = (1.f - zz) * nn + zz * hsh[j];
      hwr[j] = hnew;
      size_t trow = dir ? (size_t)(8191 - t) : (size_t)t;
      enc2[trow * 2048 + dir * 1024 + j] = hnew;
    }
    grid_barrier(region, grp, 32u, 8u, &phase, sense_base);
  }
}

// ----------------------------------------------------------------------------
template <int MODE>
__global__ __launch_bounds__(256) void k_scores(const unsigned* __restrict__ md,
                                                const float* __restrict__ enc2,
                                                const void* __restrict__ Watt,
                                                const void* __restrict__ batt,
                                                float* __restrict__ scores) {
  if (md[0] != (unsigned)MODE) return;
  int wv = threadIdx.x >> 6, lane = threadIdx.x & 63;
  int t = blockIdx.x * 4 + wv;  // grid 2048
  float a = 0.f;
#pragma unroll
  for (int k = 0; k < 8; ++k) {
    float4 e = *(const float4*)(enc2 + (size_t)t * 2048 + lane * 4 + k * 256);
    float4 ww = ld4<MODE>(Watt, 1024 + lane * 4 + k * 256);
    a += e.x * ww.x + e.y * ww.y + e.z * ww.z + e.w * ww.w;
  }
#pragma unroll
  for (int off = 32; off; off >>= 1) a += __shfl_xor(a, off);
  if (lane == 0) scores[t] = a + ld1<MODE>(batt, 0);
}

__global__ __launch_bounds__(256) void k_softmax(float* __restrict__ s) {
  __shared__ float red[8];
  int tid = threadIdx.x, wv = tid >> 6, lane = tid & 63;
  float m = -1e30f;
  for (int i = tid; i < 8192; i += 256) m = fmaxf(m, s[i]);
#pragma unroll
  for (int off = 32; off; off >>= 1) m = fmaxf(m, __shfl_xor(m, off));
  if (lane == 0) red[wv] = m;
  __syncthreads();
  m = fmaxf(fmaxf(red[0], red[1]), fmaxf(red[2], red[3]));
  float sum = 0.f;
  for (int i = tid; i < 8192; i += 256) sum += expf(s[i] - m);
#pragma unroll
  for (int off = 32; off; off >>= 1) sum += __shfl_xor(sum, off);
  if (lane == 0) red[4 + wv] = sum;
  __syncthreads();
  sum = red[4] + red[5] + red[6] + red[7];
  float inv = 1.0f / sum;
  for (int i = tid; i < 8192; i += 256) s[i] = expf(s[i] - m) * inv;
}

__global__ __launch_bounds__(256) void k_context(const float* __restrict__ attn,
                                                 const float* __restrict__ enc2,
                                                 float* __restrict__ ctx) {
  int k = blockIdx.x * 256 + threadIdx.x;  // grid 8
  float a0 = 0.f, a1 = 0.f, a2 = 0.f, a3 = 0.f;
  for (int t = 0; t < 8192; t += 4) {
    a0 += attn[t] * enc2[(size_t)t * 2048 + k];
    a1 += attn[t + 1] * enc2[(size_t)(t + 1) * 2048 + k];
    a2 += attn[t + 2] * enc2[(size_t)(t + 2) * 2048 + k];
    a3 += attn[t + 3] * enc2[(size_t)(t + 3) * 2048 + k];
  }
  ctx[k] = (a0 + a1) + (a2 + a3);
}

template <int MODE>
__global__ __launch_bounds__(256) void k_gictx(const unsigned* __restrict__ md,
                                               const void* __restrict__ dWih,
                                               const void* __restrict__ dbih,
                                               const float* __restrict__ ctx,
                                               float* __restrict__ gictx) {
  if (md[0] != (unsigned)MODE) return;
  int wv = threadIdx.x >> 6, lane = threadIdx.x & 63;
  int i = blockIdx.x * 4 + wv;  // grid 768 -> 3072
  float a = 0.f;
#pragma unroll
  for (int k = 0; k < 8; ++k) {
    float4 ww = ld4<MODE>(dWih, (size_t)i * 4096 + 2048 + lane * 4 + k * 256);
    float4 c = *(const float4*)(ctx + lane * 4 + k * 256);
    a += ww.x * c.x + ww.y * c.y + ww.z * c.z + ww.w * c.w;
  }
#pragma unroll
  for (int off = 32; off; off >>= 1) a += __shfl_xor(a, off);
  if (lane == 0) gictx[i] = a + ld1<MODE>(dbih, i);
}

__global__ void k_decinit(const float* __restrict__ hb, float* __restrict__ dh) {
  ((float4*)dh)[threadIdx.x] = ((const float4*)hb)[threadIdx.x];  // 1x256
}

// ----------------------------------------------------------------------------
// Decoder: 64 steps x 3 phases (gates->h_new | logits | log_softmax+emit).
// 256 blocks x 256 thr; block owns 4 hidden idx + 8 output idx.
// ----------------------------------------------------------------------------
template <int MODE>
__global__ __launch_bounds__(256) void k_decoder(
    const unsigned* __restrict__ md, const float* __restrict__ gictx,
    const void* __restrict__ dWih, const void* __restrict__ dWhh,
    const void* __restrict__ dbhh, const void* __restrict__ Wout,
    const void* __restrict__ bout, float* dh, float* decin, float* logits,
    unsigned* bars, void* __restrict__ out) {
  if (md[0] != (unsigned)MODE) return;
  __shared__ __align__(16) float din_sh[2048];
  __shared__ __align__(16) float dh_sh[1024];
  __shared__ float red[8];
  const int b = blockIdx.x, tid = threadIdx.x;
  const int wv = tid >> 6, lane = tid & 63;
  const int grp = b >> 4;  // 16 groups of 16
  unsigned sense_base = __hip_atomic_load(&bars[320 + grp * 16], __ATOMIC_RELAXED,
                                          __HIP_MEMORY_SCOPE_AGENT);
  unsigned phase = 0;
  for (int s = 0; s < 64; ++s) {
    float* dh_rd = dh + (s & 1) * 1024;
    float* dh_wr = dh + ((s + 1) & 1) * 1024;
    ((float4*)din_sh)[tid] = ((const float4*)decin)[tid];
    ((float4*)din_sh)[tid + 256] = ((const float4*)decin)[tid + 256];
    ((float4*)dh_sh)[tid] = ((const float4*)dh_rd)[tid];
    __syncthreads();
    const int j = b * 4 + wv;
    float ai0 = 0.f, ai1 = 0.f, ai2 = 0.f, ah0 = 0.f, ah1 = 0.f, ah2 = 0.f;
#pragma unroll
    for (int k = 0; k < 8; ++k) {
      int idx = lane + 64 * k;
      float4 dv = ((const float4*)din_sh)[idx];
      float4 q0 = ld4<MODE>(dWih, (size_t)j * 4096 + idx * 4);
      float4 q1 = ld4<MODE>(dWih, (size_t)(1024 + j) * 4096 + idx * 4);
      float4 q2 = ld4<MODE>(dWih, (size_t)(2048 + j) * 4096 + idx * 4);
      ai0 += dv.x * q0.x + dv.y * q0.y + dv.z * q0.z + dv.w * q0.w;
      ai1 += dv.x * q1.x + dv.y * q1.y + dv.z * q1.z + dv.w * q1.w;
      ai2 += dv.x * q2.x + dv.y * q2.y + dv.z * q2.z + dv.w * q2.w;
    }
#pragma unroll
    for (int k = 0; k < 4; ++k) {
      int idx = lane + 64 * k;
      float4 hv = ((const float4*)dh_sh)[idx];
      float4 q0 = ld4<MODE>(dWhh, (size_t)j * 1024 + idx * 4);
      float4 q1 = ld4<MODE>(dWhh, (size_t)(1024 + j) * 1024 + idx * 4);
      float4 q2 = ld4<MODE>(dWhh, (size_t)(2048 + j) * 1024 + idx * 4);
      ah0 += hv.x * q0.x + hv.y * q0.y + hv.z * q0.z + hv.w * q0.w;
      ah1 += hv.x * q1.x + hv.y * q1.y + hv.z * q1.z + hv.w * q1.w;
      ah2 += hv.x * q2.x + hv.y * q2.y + hv.z * q2.z + hv.w * q2.w;
    }
#pragma unroll
    for (int off = 32; off; off >>= 1) {
      ai0 += __shfl_xor(ai0, off); ai1 += __shfl_xor(ai1, off); ai2 += __shfl_xor(ai2, off);
      ah0 += __shfl_xor(ah0, off); ah1 += __shfl_xor(ah1, off); ah2 += __shfl_xor(ah2, off);
    }
    if (lane == 0) {
      float ir = gictx[j] + ai0;
      float iz = gictx[1024 + j] + ai1;
      float inn = gictx[2048 + j] + ai2;
      float hr = ah0 + ld1<MODE>(dbhh, j);
      float hz = ah1 + ld1<MODE>(dbhh, 1024 + j);
      float hn = ah2 + ld1<MODE>(dbhh, 2048 + j);
      float rr = 1.f / (1.f + expf(-(ir + hr)));
      float zz = 1.f / (1.f + expf(-(iz + hz)));
      float nn = tanhf(inn + rr * hn);
      dh_wr[j] = (1.f - zz) * nn + zz * dh_sh[j];
    }
    grid_barrier(bars, grp, 16u, 16u, &phase, sense_base);
    // phase B: logits
    ((float4*)dh_sh)[tid] = ((const float4*)dh_wr)[tid];
    __syncthreads();
    const int o = b * 8 + wv * 2;
    float l0 = 0.f, l1 = 0.f;
#pragma unroll
    for (int k = 0; k < 4; ++k) {
      int idx = lane + 64 * k;
      float4 hv = ((const float4*)dh_sh)[idx];
      float4 q0 = ld4<MODE>(Wout, (size_t)o * 1024 + idx * 4);
      float4 q1 = ld4<MODE>(Wout, (size_t)(o + 1) * 1024 + idx * 4);
      l0 += hv.x * q0.x + hv.y * q0.y + hv.z * q0.z + hv.w * q0.w;
      l1 += hv.x * q1.x + hv.y * q1.y + hv.z * q1.z + hv.w * q1.w;
    }
#pragma unroll
    for (int off = 32; off; off >>= 1) { l0 += __shfl_xor(l0, off); l1 += __shfl_xor(l1, off); }
    if (lane == 0) {
      logits[o] = l0 + ld1<MODE>(bout, o);
      logits[o + 1] = l1 + ld1<MODE>(bout, o + 1);
    }
    grid_barrier(bars, grp, 16u, 16u, &phase, sense_base);
    // phase C: log_softmax (redundant per-block reduction) + emit
    ((float4*)din_sh)[tid] = ((const float4*)logits)[tid];
    ((float4*)din_sh)[tid + 256] = ((const float4*)logits)[tid + 256];
    __syncthreads();
    float m = -1e30f;
    for (int i = tid; i < 2048; i += 256) m = fmaxf(m, din_sh[i]);
#pragma unroll
    for (int off = 32; off; off >>= 1) m = fmaxf(m, __shfl_xor(m, off));
    if (lane == 0) red[wv] = m;
    __syncthreads();
    m = fmaxf(fmaxf(red[0], red[1]), fmaxf(red[2], red[3]));
    float se = 0.f;
    for (int i = tid; i < 2048; i += 256) se += expf(din_sh[i] - m);
#pragma unroll
    for (int off = 32; off; off >>= 1) se += __shfl_xor(se, off);
    if (lane == 0) red[4 + wv] = se;
    __syncthreads();
    se = red[4] + red[5] + red[6] + red[7];
    float c = m + logf(se);
    if (tid < 8) {
      int oo = b * 8 + tid;
      float v = din_sh[oo] - c;
      st1<MODE>(out, (size_t)s * 2048 + oo, v);
      decin[oo] = v;
    }
    grid_barrier(bars, grp, 16u, 16u, &phase, sense_base);
  }
}

// ----------------------------------------------------------------------------
extern "C" void kernel_launch(void* const* d_in, const int* in_sizes, int n_in,
                              void* d_out, int out_size, void* d_ws, size_t ws_size,
                              hipStream_t stream) {
  (void)in_sizes; (void)n_in; (void)out_size; (void)ws_size;
  const void* x      = d_in[0];
  const void* h0     = d_in[1];
  const void* eWih_f = d_in[2];
  const void* eWhh_f = d_in[3];
  const void* ebih_f = d_in[4];
  const void* ebhh_f = d_in[5];
  const void* eWhh_b = d_in[7];
  const void* eWih_b = d_in[6];
  const void* ebih_b = d_in[8];
  const void* ebhh_b = d_in[9];
  const void* dWih   = d_in[10];
  const void* dWhh   = d_in[11];
  const void* dbih   = d_in[12];
  const void* dbhh   = d_in[13];
  const void* Watt   = d_in[14];
  const void* batt   = d_in[15];
  const void* Wout   = d_in[16];
  const void* bout   = d_in[17];

  float* ws = (float*)d_ws;
  bf16_t* GI    = (bf16_t*)d_ws;
  float* enc2   = ws + OFF_ENC2;
  float* hf     = ws + OFF_HF;
  float* hb     = ws + OFF_HB;
  float* scores = ws + OFF_SCORES;
  float* ctx    = ws + OFF_CTX;
  float* gictx  = ws + OFF_GICTX;
  float* dh     = ws + OFF_DH;
  float* decin  = ws + OFF_DECIN;
  float* logits = ws + OFF_LOGITS;
  unsigned* bars  = (unsigned*)(ws + OFF_BAR);
  unsigned* bars2 = bars + 1024;
  unsigned* flag  = (unsigned*)(ws + OFF_FLAG);

  k_detect<<<1, 256, 0, stream>>>((const unsigned*)x, flag);

  k_init<0><<<16, 256, 0, stream>>>(flag, hf, hb, h0, decin, bars);
  k_init<1><<<16, 256, 0, stream>>>(flag, hf, hb, h0, decin, bars);

  k_gemm_gi<0><<<dim3(128, 96), 256, 0, stream>>>(flag, x, eWih_f, eWih_b, ebih_f, ebih_b, GI);
  k_gemm_gi<1><<<dim3(128, 96), 256, 0, stream>>>(flag, x, eWih_f, eWih_b, ebih_f, ebih_b, GI);

  k_recurrence<0><<<512, 256, 0, stream>>>(flag, GI, eWhh_f, eWhh_b, ebhh_f, ebhh_b, enc2, hf, hb, bars);
  k_recurrence<1><<<512, 256, 0, stream>>>(flag, GI, eWhh_f, eWhh_b, ebhh_f, ebhh_b, enc2, hf, hb, bars);

  k_scores<0><<<2048, 256, 0, stream>>>(flag, enc2, Watt, batt, scores);
  k_scores<1><<<2048, 256, 0, stream>>>(flag, enc2, Watt, batt, scores);

  k_softmax<<<1, 256, 0, stream>>>(scores);
  k_context<<<8, 256, 0, stream>>>(scores, enc2, ctx);

  k_gictx<0><<<768, 256, 0, stream>>>(flag, dWih, dbih, ctx, gictx);
  k_gictx<1><<<768, 256, 0, stream>>>(flag, dWih, dbih, ctx, gictx);

  k_decinit<<<1, 256, 0, stream>>>(hb, dh);

  k_decoder<0><<<256, 256, 0, stream>>>(flag, gictx, dWih, dWhh, dbhh, Wout, bout, dh, decin, logits, bars2, d_out);
  k_decoder<1><<<256, 256, 0, stream>>>(flag, gictx, dWih, dWhh, dbhh, Wout, bout, dh, decin, logits, bars2, d_out);
}

// Round 6
// 22996.114 us; speedup vs baseline: 6.6155x; 6.6155x over previous
//
#include <hip/hip_runtime.h>
#include <hip/hip_bf16.h>

// ============================================================================
// Seq2seq: bi-GRU encoder (T=8192, H=I=1024) + attention decoder (L=64).
// Inputs/outputs are fp32 (proven: round 5 passed reading fp32, absmax 0.0625).
//  - gi = x@Wih.T batched into one GEMM (8192x1024 @ 1024x6144), bf16 scratch.
//  - attention softmax shift-invariance => attn/context constant across all 64
//    decoder steps; computed once.
//  - recurrence sync (round-5 lesson): the hierarchical counter barrier cost
//    17.8us/step (32 serialized agent-scope RMWs/line + acquire fence). Now
//    each h element is published as an 8B atomic word [epoch|fp32]; arrival is
//    one parallel relaxed store, detection is 1 word/thread polled for
//    epoch==t. Double-buffered by parity; all-to-all reads each step make
//    exact-match polling race-free (writer at most 2 steps ahead).
// ============================================================================
typedef __hip_bfloat16 bf16_t;
typedef unsigned long long u64;
struct alignas(8) bh4 { bf16_t v[4]; };
__device__ __forceinline__ float bf2f(bf16_t v) { return __bfloat162float(v); }

// workspace offsets (floats); total ~168 MB (proven in-bounds)
static constexpr size_t OFF_ENC2   = 25165824;                 // after bf16 GI
static constexpr size_t OFF_SCORES = OFF_ENC2 + 16777216;
static constexpr size_t OFF_CTX    = OFF_SCORES + 8192;
static constexpr size_t OFF_GICTX  = OFF_CTX + 2048;           // 3072 (+pad)
static constexpr size_t OFF_PUB    = OFF_GICTX + 4096;         // u64 region
// u64 region: pub_f[2][1024] | pub_b[2][1024] | hpub[2][1024] | lpub[2][2048]

static constexpr unsigned TAG_BAD = 0x7FFFFFFFu;

__device__ __forceinline__ u64 pub_load(const u64* p) {
  return __hip_atomic_load(p, __ATOMIC_RELAXED, __HIP_MEMORY_SCOPE_AGENT);
}
__device__ __forceinline__ void pub_store(u64* p, u64 v) {
  __hip_atomic_store(p, v, __ATOMIC_RELAXED, __HIP_MEMORY_SCOPE_AGENT);
}
__device__ __forceinline__ u64 pack(unsigned tag, float f) {
  union { float f; unsigned u; } c; c.f = f;
  return ((u64)tag << 32) | c.u;
}
__device__ __forceinline__ float unpack(u64 w) {
  union { unsigned u; float f; } c; c.u = (unsigned)w;
  return c.f;
}

// ----------------------------------------------------------------------------
__global__ __launch_bounds__(1024) void k_init(const float* __restrict__ h0,
                                               u64* pub) {
  int i = blockIdx.x * 1024 + threadIdx.x;  // grid 10 -> 10240 words
  if (i < 1024)       pub[i] = pack(0u, h0[i]);                 // pub_f[0]
  else if (i < 2048)  pub[i] = pack(TAG_BAD, 0.f);              // pub_f[1]
  else if (i < 3072)  pub[i] = pack(0u, h0[1024 + (i - 2048)]); // pub_b[0]
  else if (i < 10240) pub[i] = pack(TAG_BAD, 0.f);              // rest
}

// ----------------------------------------------------------------------------
// GI = X @ [Wih_f; Wih_b]^T + bias.  64x64 tile, 4x4 microtile, fp32 math,
// bf16 store (scratch only).
// ----------------------------------------------------------------------------
__global__ __launch_bounds__(256) void k_gemm_gi(
    const float* __restrict__ X, const float* __restrict__ Wf,
    const float* __restrict__ Wb, const float* __restrict__ bf,
    const float* __restrict__ bb, bf16_t* __restrict__ GI) {
  __shared__ __align__(16) float As[16][68];
  __shared__ __align__(16) float Bs[16][68];
  const int m0 = blockIdx.x * 64;
  const int n0 = blockIdx.y * 64;
  const int tid = threadIdx.x;
  const int tx = tid & 15, ty = tid >> 4;
  const int lm = tid >> 2, lk = (tid & 3) * 4;
  const float* Wsel = (n0 < 3072) ? Wf : Wb;
  const float* bsel = (n0 < 3072) ? bf : bb;
  const int nadj = (n0 < 3072) ? n0 : (n0 - 3072);
  float acc[4][4];
#pragma unroll
  for (int i = 0; i < 4; ++i)
#pragma unroll
    for (int j = 0; j < 4; ++j) acc[i][j] = 0.f;
  for (int k0 = 0; k0 < 1024; k0 += 16) {
    float4 av = *(const float4*)(X + (size_t)(m0 + lm) * 1024 + k0 + lk);
    float4 bv = *(const float4*)(Wsel + (size_t)(nadj + lm) * 1024 + k0 + lk);
    __syncthreads();
    As[lk + 0][lm] = av.x; As[lk + 1][lm] = av.y; As[lk + 2][lm] = av.z; As[lk + 3][lm] = av.w;
    Bs[lk + 0][lm] = bv.x; Bs[lk + 1][lm] = bv.y; Bs[lk + 2][lm] = bv.z; Bs[lk + 3][lm] = bv.w;
    __syncthreads();
#pragma unroll
    for (int kk = 0; kk < 16; ++kk) {
      float4 a = *(const float4*)&As[kk][ty * 4];
      float4 b = *(const float4*)&Bs[kk][tx * 4];
      acc[0][0] += a.x * b.x; acc[0][1] += a.x * b.y; acc[0][2] += a.x * b.z; acc[0][3] += a.x * b.w;
      acc[1][0] += a.y * b.x; acc[1][1] += a.y * b.y; acc[1][2] += a.y * b.z; acc[1][3] += a.y * b.w;
      acc[2][0] += a.z * b.x; acc[2][1] += a.z * b.y; acc[2][2] += a.z * b.z; acc[2][3] += a.z * b.w;
      acc[3][0] += a.w * b.x; acc[3][1] += a.w * b.y; acc[3][2] += a.w * b.z; acc[3][3] += a.w * b.w;
    }
  }
  float b0 = bsel[nadj + tx * 4 + 0], b1 = bsel[nadj + tx * 4 + 1];
  float b2 = bsel[nadj + tx * 4 + 2], b3 = bsel[nadj + tx * 4 + 3];
#pragma unroll
  for (int i = 0; i < 4; ++i) {
    bh4 o;
    o.v[0] = __float2bfloat16(acc[i][0] + b0);
    o.v[1] = __float2bfloat16(acc[i][1] + b1);
    o.v[2] = __float2bfloat16(acc[i][2] + b2);
    o.v[3] = __float2bfloat16(acc[i][3] + b3);
    *(bh4*)(GI + (size_t)(m0 + ty * 4 + i) * 6144 + n0 + tx * 4) = o;
  }
}

// ----------------------------------------------------------------------------
// Both GRU recurrences. 256 blocks x 1024 thr (1 block/CU, 96 KB Whh in LDS).
// Block owns 8 hidden idx = 24 Whh rows. Wave w: row w (+ row 16+w if w<8).
// Per step: poll 1 word/thread -> LDS h -> dots -> gates (threads 0..7) ->
// publish 8 words. Two __syncthreads/step; no counters, no fences.
// ----------------------------------------------------------------------------
__global__ __launch_bounds__(1024, 1) void k_recurrence(
    const bf16_t* __restrict__ GI, const float* __restrict__ Whh_f,
    const float* __restrict__ Whh_b, const float* __restrict__ bhh_f,
    const float* __restrict__ bhh_b, float* __restrict__ enc2,
    u64* pub_f, u64* pub_b) {
  __shared__ __align__(16) float w[24][1024];   // 96 KB
  __shared__ __align__(16) float hsh[1024];
  __shared__ float rowsum[24];
  __shared__ float bsh[24];
  __shared__ float gish[24];
  const int blk = blockIdx.x;      // 0..255
  const int dir = blk >> 7;        // 128 blocks/direction
  const int bb = blk & 127;
  const int j0 = bb * 8;
  const int tid = threadIdx.x;
  const int wv = tid >> 6, lane = tid & 63;
  const float* Whh = dir ? Whh_b : Whh_f;
  const float* bhh = dir ? bhh_b : bhh_f;
  u64* pub = dir ? pub_b : pub_f;

  for (int i = tid; i < 24 * 256; i += 1024) {   // stage 24 rows (6 float4/thr)
    int r = i >> 8, c4 = i & 255;
    int g = r >> 3, jj = r & 7;
    *(float4*)&w[r][c4 * 4] =
        *(const float4*)(Whh + (size_t)(g * 1024 + j0 + jj) * 1024 + c4 * 4);
  }
  if (tid < 24) {
    int g = tid >> 3, jj = tid & 7;
    bsh[tid] = bhh[g * 1024 + j0 + jj];
  }
  float gpre = 0.f;
  size_t gcol = 0;
  if (tid < 24) {
    int g = tid >> 3, jj = tid & 7;
    gcol = (size_t)(dir ? 3072 : 0) + g * 1024 + j0 + jj;
    gpre = bf2f(GI[(size_t)(dir ? 8191 : 0) * 6144 + gcol]);
  }
  __syncthreads();

  for (int t = 0; t < 8192; ++t) {
    {  // poll h (word tid) for epoch t; data arrives in the word
      u64* src = pub + (size_t)(t & 1) * 1024 + tid;
      u64 wd = pub_load(src);
      while ((unsigned)(wd >> 32) != (unsigned)t) {
        __builtin_amdgcn_s_sleep(1);
        wd = pub_load(src);
      }
      hsh[tid] = unpack(wd);
    }
    __syncthreads();                 // sync#1: h staged; prior-step gates done
    if (tid < 24) {
      gish[tid] = gpre;
      if (t < 8191) {                // prefetch next gi during this step
        size_t row = dir ? (size_t)(8190 - t) : (size_t)(t + 1);
        gpre = bf2f(GI[row * 6144 + gcol]);
      }
    }
    float a0 = 0.f, a1 = 0.f;
    {
      const float4* hp = (const float4*)hsh;
      const float4* w0 = (const float4*)&w[wv][0];
#pragma unroll
      for (int q = 0; q < 4; ++q) {
        int idx = lane + 64 * q;
        float4 hv = hp[idx], x0 = w0[idx];
        a0 += hv.x * x0.x + hv.y * x0.y + hv.z * x0.z + hv.w * x0.w;
      }
      if (wv < 8) {
        const float4* w1 = (const float4*)&w[16 + wv][0];
#pragma unroll
        for (int q = 0; q < 4; ++q) {
          int idx = lane + 64 * q;
          float4 hv = hp[idx], x1 = w1[idx];
          a1 += hv.x * x1.x + hv.y * x1.y + hv.z * x1.z + hv.w * x1.w;
        }
      }
    }
#pragma unroll
    for (int off = 32; off; off >>= 1) {
      a0 += __shfl_xor(a0, off);
      a1 += __shfl_xor(a1, off);
    }
    if (lane == 0) {
      rowsum[wv] = a0;
      if (wv < 8) rowsum[16 + wv] = a1;
    }
    __syncthreads();                 // sync#2: rowsums ready
    if (tid < 8) {
      int jj = tid, j = j0 + jj;
      float hr = rowsum[jj] + bsh[jj];
      float hz = rowsum[8 + jj] + bsh[8 + jj];
      float hn = rowsum[16 + jj] + bsh[16 + jj];
      float ir = gish[jj], iz = gish[8 + jj], inn = gish[16 + jj];
      float rr = 1.f / (1.f + expf(-(ir + hr)));
      float zz = 1.f / (1.f + expf(-(iz + hz)));
      float nn = tanhf(inn + rr * hn);
      float hnew = (1.f - zz) * nn + zz * hsh[j];
      pub_store(pub + (size_t)((t + 1) & 1) * 1024 + j, pack((unsigned)(t + 1), hnew));
      size_t trow = dir ? (size_t)(8191 - t) : (size_t)t;
      enc2[trow * 2048 + dir * 1024 + j] = hnew;
    }
    // no end-of-loop sync needed: next poll's hsh/gish/rowsum writes are
    // ordered behind sync#1/#2 of step t+1, which require this step's gates.
  }
}

// ----------------------------------------------------------------------------
__global__ __launch_bounds__(256) void k_scores(const float* __restrict__ enc2,
                                                const float* __restrict__ Watt,
                                                const float* __restrict__ batt,
                                                float* __restrict__ scores) {
  int wv = threadIdx.x >> 6, lane = threadIdx.x & 63;
  int t = blockIdx.x * 4 + wv;  // grid 2048
  const float* We = Watt + 1024;
  float a = 0.f;
#pragma unroll
  for (int k = 0; k < 8; ++k) {
    float4 e = *(const float4*)(enc2 + (size_t)t * 2048 + lane * 4 + k * 256);
    float4 ww = *(const float4*)(We + lane * 4 + k * 256);
    a += e.x * ww.x + e.y * ww.y + e.z * ww.z + e.w * ww.w;
  }
#pragma unroll
  for (int off = 32; off; off >>= 1) a += __shfl_xor(a, off);
  if (lane == 0) scores[t] = a + batt[0];
}

__global__ __launch_bounds__(256) void k_softmax(float* __restrict__ s) {
  __shared__ float red[8];
  int tid = threadIdx.x, wv = tid >> 6, lane = tid & 63;
  float m = -1e30f;
  for (int i = tid; i < 8192; i += 256) m = fmaxf(m, s[i]);
#pragma unroll
  for (int off = 32; off; off >>= 1) m = fmaxf(m, __shfl_xor(m, off));
  if (lane == 0) red[wv] = m;
  __syncthreads();
  m = fmaxf(fmaxf(red[0], red[1]), fmaxf(red[2], red[3]));
  float sum = 0.f;
  for (int i = tid; i < 8192; i += 256) sum += expf(s[i] - m);
#pragma unroll
  for (int off = 32; off; off >>= 1) sum += __shfl_xor(sum, off);
  if (lane == 0) red[4 + wv] = sum;
  __syncthreads();
  sum = red[4] + red[5] + red[6] + red[7];
  float inv = 1.0f / sum;
  for (int i = tid; i < 8192; i += 256) s[i] = expf(s[i] - m) * inv;
}

__global__ __launch_bounds__(256) void k_context(const float* __restrict__ attn,
                                                 const float* __restrict__ enc2,
                                                 float* __restrict__ ctx) {
  int k = blockIdx.x * 256 + threadIdx.x;  // grid 8
  float a0 = 0.f, a1 = 0.f, a2 = 0.f, a3 = 0.f;
  for (int t = 0; t < 8192; t += 4) {
    a0 += attn[t] * enc2[(size_t)t * 2048 + k];
    a1 += attn[t + 1] * enc2[(size_t)(t + 1) * 2048 + k];
    a2 += attn[t + 2] * enc2[(size_t)(t + 2) * 2048 + k];
    a3 += attn[t + 3] * enc2[(size_t)(t + 3) * 2048 + k];
  }
  ctx[k] = (a0 + a1) + (a2 + a3);
}

__global__ __launch_bounds__(256) void k_gictx(const float* __restrict__ dWih,
                                               const float* __restrict__ dbih,
                                               const float* __restrict__ ctx,
                                               float* __restrict__ gictx) {
  int wv = threadIdx.x >> 6, lane = threadIdx.x & 63;
  int i = blockIdx.x * 4 + wv;  // grid 768 -> 3072
  float a = 0.f;
#pragma unroll
  for (int k = 0; k < 8; ++k) {
    float4 ww = *(const float4*)(dWih + (size_t)i * 4096 + 2048 + lane * 4 + k * 256);
    float4 c = *(const float4*)(ctx + lane * 4 + k * 256);
    a += ww.x * c.x + ww.y * c.y + ww.z * c.z + ww.w * c.w;
  }
#pragma unroll
  for (int off = 32; off; off >>= 1) a += __shfl_xor(a, off);
  if (lane == 0) gictx[i] = a + dbih[i];
}

// seed decoder h state (tag 0) from bwd final h (tag 8192, parity 0)
__global__ void k_decinit(const u64* __restrict__ pub_b, u64* hpub) {
  int i = threadIdx.x;  // 1x1024
  hpub[i] = pack(0u, unpack(pub_b[i]));
}

// ----------------------------------------------------------------------------
// Decoder: 64 steps, 128 blocks x 1024 thr. Block owns 8 hidden + 16 out rows.
// Phase A: poll h(tag s) + logits(tag s) -> local log-softmax (redundant,
//   deterministic) -> out for step s-1 -> GRU gates -> publish h(tag s+1).
// Phase B: poll h(tag s+1) -> 16 logit rows -> publish logits(tag s+1).
// Final: poll logits(tag 64) -> out for step 63.
// ----------------------------------------------------------------------------
__global__ __launch_bounds__(1024, 1) void k_decoder(
    const float* __restrict__ gictx, const float* __restrict__ dWih,
    const float* __restrict__ dWhh, const float* __restrict__ dbhh,
    const float* __restrict__ Wout, const float* __restrict__ bout,
    u64* hpub, u64* lpub, float* __restrict__ out) {
  __shared__ __align__(16) float hsh[1024];
  __shared__ __align__(16) float lsh[2048];
  __shared__ __align__(16) float dsh[2048];
  __shared__ float rsA[24], rsB[24];
  __shared__ float red[32];
  __shared__ float gctx[24], bsh[24], bo[16];
  const int bb = blockIdx.x;           // 128 blocks
  const int j0 = bb * 8, o0 = bb * 16;
  const int tid = threadIdx.x, wv = tid >> 6, lane = tid & 63;
  if (tid < 24) {
    int g = tid >> 3, jj = tid & 7;
    gctx[tid] = gictx[g * 1024 + j0 + jj];
    bsh[tid] = dbhh[g * 1024 + j0 + jj];
  }
  if (tid < 16) bo[tid] = bout[o0 + tid];
  __syncthreads();

  for (int s = 0; s < 64; ++s) {
    {  // poll h state (tag s)
      u64* hp = hpub + (size_t)(s & 1) * 1024 + tid;
      u64 wd = pub_load(hp);
      while ((unsigned)(wd >> 32) != (unsigned)s) {
        __builtin_amdgcn_s_sleep(1);
        wd = pub_load(hp);
      }
      hsh[tid] = unpack(wd);
    }
    if (s > 0) {  // poll logits (tag s)
      u64* lp = lpub + (size_t)(s & 1) * 2048;
#pragma unroll
      for (int q = 0; q < 2; ++q) {
        int i = tid + q * 1024;
        u64 wd = pub_load(lp + i);
        while ((unsigned)(wd >> 32) != (unsigned)s) {
          __builtin_amdgcn_s_sleep(1);
          wd = pub_load(lp + i);
        }
        lsh[i] = unpack(wd);
      }
    }
    __syncthreads();
    if (s > 0) {  // log-softmax over lsh (redundant per block, deterministic)
      float m = fmaxf(lsh[tid], lsh[tid + 1024]);
#pragma unroll
      for (int off = 32; off; off >>= 1) m = fmaxf(m, __shfl_xor(m, off));
      if (lane == 0) red[wv] = m;
      __syncthreads();
      m = -1e30f;
      for (int i = 0; i < 16; ++i) m = fmaxf(m, red[i]);
      float e = expf(lsh[tid] - m) + expf(lsh[tid + 1024] - m);
#pragma unroll
      for (int off = 32; off; off >>= 1) e += __shfl_xor(e, off);
      if (lane == 0) red[16 + wv] = e;
      __syncthreads();
      float se = 0.f;
      for (int i = 0; i < 16; ++i) se += red[16 + i];
      float c = m + logf(se);
      dsh[tid] = lsh[tid] - c;
      dsh[tid + 1024] = lsh[tid + 1024] - c;
    } else {
      dsh[tid] = 0.f;
      dsh[tid + 1024] = 0.f;
    }
    __syncthreads();
    if (s > 0 && tid < 16) out[(size_t)(s - 1) * 2048 + o0 + tid] = dsh[o0 + tid];
    // gate dots: combo r = g*8+jj; wave wv -> combo wv (+16+wv if wv<8)
    float aA0 = 0.f, aB0 = 0.f, aA1 = 0.f, aB1 = 0.f;
    {
      int g = wv >> 3, jj = wv & 7;
      const float4* rowI = (const float4*)(dWih + (size_t)(g * 1024 + j0 + jj) * 4096);
      const float4* rowH = (const float4*)(dWhh + (size_t)(g * 1024 + j0 + jj) * 1024);
      const float4* dp = (const float4*)dsh;
      const float4* hp = (const float4*)hsh;
#pragma unroll
      for (int q = 0; q < 8; ++q) {
        int idx = lane + 64 * q;
        float4 d = dp[idx], wi = rowI[idx];
        aA0 += d.x * wi.x + d.y * wi.y + d.z * wi.z + d.w * wi.w;
      }
#pragma unroll
      for (int q = 0; q < 4; ++q) {
        int idx = lane + 64 * q;
        float4 h = hp[idx], wh = rowH[idx];
        aB0 += h.x * wh.x + h.y * wh.y + h.z * wh.z + h.w * wh.w;
      }
      if (wv < 8) {
        const float4* rowI2 = (const float4*)(dWih + (size_t)(2 * 1024 + j0 + wv) * 4096);
        const float4* rowH2 = (const float4*)(dWhh + (size_t)(2 * 1024 + j0 + wv) * 1024);
#pragma unroll
        for (int q = 0; q < 8; ++q) {
          int idx = lane + 64 * q;
          float4 d = dp[idx], wi = rowI2[idx];
          aA1 += d.x * wi.x + d.y * wi.y + d.z * wi.z + d.w * wi.w;
        }
#pragma unroll
        for (int q = 0; q < 4; ++q) {
          int idx = lane + 64 * q;
          float4 h = hp[idx], wh = rowH2[idx];
          aB1 += h.x * wh.x + h.y * wh.y + h.z * wh.z + h.w * wh.w;
        }
      }
    }
#pragma unroll
    for (int off = 32; off; off >>= 1) {
      aA0 += __shfl_xor(aA0, off); aB0 += __shfl_xor(aB0, off);
      aA1 += __shfl_xor(aA1, off); aB1 += __shfl_xor(aB1, off);
    }
    if (lane == 0) {
      rsA[wv] = aA0; rsB[wv] = aB0;
      if (wv < 8) { rsA[16 + wv] = aA1; rsB[16 + wv] = aB1; }
    }
    __syncthreads();
    if (tid < 8) {
      int jj = tid, j = j0 + jj;
      float ir = gctx[jj] + rsA[jj];
      float iz = gctx[8 + jj] + rsA[8 + jj];
      float inn = gctx[16 + jj] + rsA[16 + jj];
      float hr = rsB[jj] + bsh[jj];
      float hz = rsB[8 + jj] + bsh[8 + jj];
      float hn = rsB[16 + jj] + bsh[16 + jj];
      float rr = 1.f / (1.f + expf(-(ir + hr)));
      float zz = 1.f / (1.f + expf(-(iz + hz)));
      float nn = tanhf(inn + rr * hn);
      float hnew = (1.f - zz) * nn + zz * hsh[j];
      pub_store(hpub + (size_t)((s + 1) & 1) * 1024 + j, pack((unsigned)(s + 1), hnew));
    }
    __syncthreads();
    {  // phase B: poll h(tag s+1), compute 16 logit rows, publish
      u64* hp = hpub + (size_t)((s + 1) & 1) * 1024 + tid;
      u64 wd = pub_load(hp);
      while ((unsigned)(wd >> 32) != (unsigned)(s + 1)) {
        __builtin_amdgcn_s_sleep(1);
        wd = pub_load(hp);
      }
      hsh[tid] = unpack(wd);
    }
    __syncthreads();
    {
      int o = o0 + wv;
      const float4* rowO = (const float4*)(Wout + (size_t)o * 1024);
      const float4* hp = (const float4*)hsh;
      float l = 0.f;
#pragma unroll
      for (int q = 0; q < 4; ++q) {
        int idx = lane + 64 * q;
        float4 h = hp[idx], wo = rowO[idx];
        l += h.x * wo.x + h.y * wo.y + h.z * wo.z + h.w * wo.w;
      }
#pragma unroll
      for (int off = 32; off; off >>= 1) l += __shfl_xor(l, off);
      if (lane == 0)
        pub_store(lpub + (size_t)((s + 1) & 1) * 2048 + o, pack((unsigned)(s + 1), l + bo[wv]));
    }
    __syncthreads();
  }
  {  // final: logits tag 64 (parity 0) -> out step 63
    u64* lp = lpub + 0;
#pragma unroll
    for (int q = 0; q < 2; ++q) {
      int i = tid + q * 1024;
      u64 wd = pub_load(lp + i);
      while ((unsigned)(wd >> 32) != 64u) {
        __builtin_amdgcn_s_sleep(1);
        wd = pub_load(lp + i);
      }
      lsh[i] = unpack(wd);
    }
  }
  __syncthreads();
  float m = fmaxf(lsh[tid], lsh[tid + 1024]);
#pragma unroll
  for (int off = 32; off; off >>= 1) m = fmaxf(m, __shfl_xor(m, off));
  if (lane == 0) red[wv] = m;
  __syncthreads();
  m = -1e30f;
  for (int i = 0; i < 16; ++i) m = fmaxf(m, red[i]);
  float e = expf(lsh[tid] - m) + expf(lsh[tid + 1024] - m);
#pragma unroll
  for (int off = 32; off; off >>= 1) e += __shfl_xor(e, off);
  if (lane == 0) red[16 + wv] = e;
  __syncthreads();
  float se = 0.f;
  for (int i = 0; i < 16; ++i) se += red[16 + i];
  float c = m + logf(se);
  if (tid < 16) out[(size_t)63 * 2048 + o0 + tid] = lsh[o0 + tid] - c;
}

// ----------------------------------------------------------------------------
extern "C" void kernel_launch(void* const* d_in, const int* in_sizes, int n_in,
                              void* d_out, int out_size, void* d_ws, size_t ws_size,
                              hipStream_t stream) {
  (void)in_sizes; (void)n_in; (void)out_size; (void)ws_size;
  const float* x      = (const float*)d_in[0];
  const float* h0     = (const float*)d_in[1];
  const float* eWih_f = (const float*)d_in[2];
  const float* eWhh_f = (const float*)d_in[3];
  const float* ebih_f = (const float*)d_in[4];
  const float* ebhh_f = (const float*)d_in[5];
  const float* eWih_b = (const float*)d_in[6];
  const float* eWhh_b = (const float*)d_in[7];
  const float* ebih_b = (const float*)d_in[8];
  const float* ebhh_b = (const float*)d_in[9];
  const float* dWih   = (const float*)d_in[10];
  const float* dWhh   = (const float*)d_in[11];
  const float* dbih   = (const float*)d_in[12];
  const float* dbhh   = (const float*)d_in[13];
  const float* Watt   = (const float*)d_in[14];
  const float* batt   = (const float*)d_in[15];
  const float* Wout   = (const float*)d_in[16];
  const float* bout   = (const float*)d_in[17];

  float* ws = (float*)d_ws;
  bf16_t* GI    = (bf16_t*)d_ws;
  float* enc2   = ws + OFF_ENC2;
  float* scores = ws + OFF_SCORES;
  float* ctx    = ws + OFF_CTX;
  float* gictx  = ws + OFF_GICTX;
  u64* pub      = (u64*)(ws + OFF_PUB);
  u64* pub_f = pub;            // [2][1024]
  u64* pub_b = pub + 2048;     // [2][1024]
  u64* hpub  = pub + 4096;     // [2][1024]
  u64* lpub  = pub + 6144;     // [2][2048]
  float* out = (float*)d_out;

  k_init<<<10, 1024, 0, stream>>>(h0, pub);
  k_gemm_gi<<<dim3(128, 96), 256, 0, stream>>>(x, eWih_f, eWih_b, ebih_f, ebih_b, GI);
  k_recurrence<<<256, 1024, 0, stream>>>(GI, eWhh_f, eWhh_b, ebhh_f, ebhh_b, enc2, pub_f, pub_b);
  k_scores<<<2048, 256, 0, stream>>>(enc2, Watt, batt, scores);
  k_softmax<<<1, 256, 0, stream>>>(scores);
  k_context<<<8, 256, 0, stream>>>(scores, enc2, ctx);
  k_gictx<<<768, 256, 0, stream>>>(dWih, dbih, ctx, gictx);
  k_decinit<<<1, 1024, 0, stream>>>(pub_b, hpub);
  k_decoder<<<128, 1024, 0, stream>>>(gictx, dWih, dWhh, dbhh, Wout, bout, hpub, lpub, out);
}